// Round 2
// baseline (1127.960 us; speedup 1.0000x reference)
//
#include <hip/hip_runtime.h>
#include <hip/hip_bf16.h>

// LiteMLA: B=8, C=256, H=W=64, N=HW=4096, td=256, d=8, heads=64
// qkv: (8,768,4096)  dw/agg: (8,768,4096)  kv: (8,64,8,9)

#define HW 4096
#define ATT_EPS 1e-15f
#define BN_EPS 1e-6f

// ---------------- K1: qkv = w_qkv(768x256) @ x(b,256,4096) ----------------
// block 256 thr; each thread: 16 o x 4 n (float4). grid (4 ntiles, 48 otiles, 8 b)
__global__ __launch_bounds__(256) void qkv_gemm(const float* __restrict__ x,
                                                const float* __restrict__ w,
                                                float* __restrict__ qkv) {
    const int b  = blockIdx.z;
    const int o0 = blockIdx.y * 16;
    const int nb = blockIdx.x * 1024;           // floats
    const int t  = threadIdx.x;

    const float4* xp = (const float4*)(x + ((size_t)b * 256) * HW + nb) + t;
    const float*  wp = w + o0 * 256;            // block-uniform -> scalar loads

    float4 acc[16];
#pragma unroll
    for (int i = 0; i < 16; i++) acc[i] = make_float4(0.f, 0.f, 0.f, 0.f);

#pragma unroll 2
    for (int c = 0; c < 256; c++) {
        float4 xv = xp[c * 1024];
#pragma unroll
        for (int oo = 0; oo < 16; oo++) {
            float wv = wp[oo * 256 + c];
            acc[oo].x += wv * xv.x;
            acc[oo].y += wv * xv.y;
            acc[oo].z += wv * xv.z;
            acc[oo].w += wv * xv.w;
        }
    }
    float4* po = (float4*)(qkv + ((size_t)b * 768 + o0) * HW + nb) + t;
#pragma unroll
    for (int oo = 0; oo < 16; oo++) po[oo * 1024] = acc[oo];
}

// ---------------- K2: depthwise 5x5, pad 2 ----------------
// block 256 = 64x * 4y; grid (16 ytiles, 768 ch, 8 b)
__global__ __launch_bounds__(256) void dw_conv(const float* __restrict__ qkv,
                                               const float* __restrict__ wdw,
                                               float* __restrict__ dst) {
    __shared__ float tile[8][64];   // rows y0-2 .. y0+5
    __shared__ float wk[25];
    const int b  = blockIdx.z;
    const int ch = blockIdx.y;
    const int y0 = blockIdx.x * 4;
    const int tx = threadIdx.x & 63;
    const int ty = threadIdx.x >> 6;

    const float* src = qkv + ((size_t)b * 768 + ch) * HW;
    for (int i = threadIdx.x; i < 512; i += 256) {
        int r = i >> 6, xx = i & 63;
        int y = y0 - 2 + r;
        tile[r][xx] = (y >= 0 && y < 64) ? src[y * 64 + xx] : 0.f;
    }
    if (threadIdx.x < 25) wk[threadIdx.x] = wdw[ch * 25 + threadIdx.x];
    __syncthreads();

    float acc = 0.f;
#pragma unroll
    for (int dy = 0; dy < 5; dy++) {
#pragma unroll
        for (int dx = 0; dx < 5; dx++) {
            int xx = tx + dx - 2;
            float v = (xx >= 0 && xx < 64) ? tile[ty + dy][xx] : 0.f;
            acc += wk[dy * 5 + dx] * v;
        }
    }
    dst[((size_t)b * 768 + ch) * HW + (y0 + ty) * 64 + tx] = acc;
}

// ---------------- K3: grouped pointwise 8x8, in place ----------------
// grid (16 ntiles, 96 g, 8 b), block 256
__global__ __launch_bounds__(256) void agg_pw(float* __restrict__ buf,
                                              const float* __restrict__ wpw) {
    __shared__ float wl[64];
    const int b = blockIdx.z, g = blockIdx.y;
    const int n = blockIdx.x * 256 + threadIdx.x;
    if (threadIdx.x < 64) wl[threadIdx.x] = wpw[g * 64 + threadIdx.x];
    __syncthreads();

    float* base = buf + ((size_t)b * 768 + g * 8) * HW + n;
    float d[8];
#pragma unroll
    for (int i = 0; i < 8; i++) d[i] = base[(size_t)i * HW];
#pragma unroll
    for (int o = 0; o < 8; o++) {
        float acc = 0.f;
#pragma unroll
        for (int i = 0; i < 8; i++) acc += wl[o * 8 + i] * d[i];
        base[(size_t)o * HW] = acc;
    }
}

// ---------------- K4: kv[d][e] = sum_n relu(k[n,d]) * vpad[n,e] ----------------
// grid (64 h, 8 b), block 256. kv out: (b*64+h)*72 + d*9+e
__global__ __launch_bounds__(256) void kv_pass(const float* __restrict__ qkv,
                                               const float* __restrict__ agg,
                                               float* __restrict__ kvout) {
    const int h = blockIdx.x, b = blockIdx.y;
    const float* buf = (h < 32) ? qkv : agg;
    const int cbase  = (h < 32) ? h * 24 : h * 24 - 768;
    const float* kp = buf + ((size_t)b * 768 + cbase + 8) * HW;
    const float* vp = buf + ((size_t)b * 768 + cbase + 16) * HW;

    float acc[8][9];
#pragma unroll
    for (int d = 0; d < 8; d++)
#pragma unroll
        for (int e = 0; e < 9; e++) acc[d][e] = 0.f;

    for (int n = threadIdx.x; n < HW; n += 256) {
        float kk[8], vv[8];
#pragma unroll
        for (int d = 0; d < 8; d++) kk[d] = fmaxf(kp[(size_t)d * HW + n], 0.f);
#pragma unroll
        for (int e = 0; e < 8; e++) vv[e] = vp[(size_t)e * HW + n];
#pragma unroll
        for (int d = 0; d < 8; d++) {
#pragma unroll
            for (int e = 0; e < 8; e++) acc[d][e] += kk[d] * vv[e];
            acc[d][8] += kk[d];
        }
    }

    __shared__ float red[4][72];
    const int lane = threadIdx.x & 63, wv = threadIdx.x >> 6;
#pragma unroll
    for (int d = 0; d < 8; d++) {
#pragma unroll
        for (int e = 0; e < 9; e++) {
            float v = acc[d][e];
            v += __shfl_xor(v, 1);
            v += __shfl_xor(v, 2);
            v += __shfl_xor(v, 4);
            v += __shfl_xor(v, 8);
            v += __shfl_xor(v, 16);
            v += __shfl_xor(v, 32);
            if (lane == 0) red[wv][d * 9 + e] = v;
        }
    }
    __syncthreads();
    if (threadIdx.x < 72) {
        float s = red[0][threadIdx.x] + red[1][threadIdx.x] +
                  red[2][threadIdx.x] + red[3][threadIdx.x];
        kvout[((size_t)(b * 64 + h)) * 72 + threadIdx.x] = s;
    }
}

// ---------------- K5: att = (relu(q)@kv)/den, p = w_proj@att, BN, +x ----------------
// grid (16 px-tiles of 256, 4 og, 8 b), block 256. Each thread: 1 px, 64 o.
// og now BLOCK-uniform (blockIdx.y) -> wproj accesses compile to s_load.
__global__ __launch_bounds__(256) void att_proj(const float* __restrict__ qkv,
                                                const float* __restrict__ agg,
                                                const float* __restrict__ kvbuf,
                                                const float* __restrict__ wproj,
                                                const float* __restrict__ gamma,
                                                const float* __restrict__ beta,
                                                const float* __restrict__ mean,
                                                const float* __restrict__ var,
                                                const float* __restrict__ x,
                                                float* __restrict__ out) {
    __shared__ float kv_l[64 * 72];       // 18 KB
    const int b  = blockIdx.z;
    const int og = blockIdx.y;            // block-uniform output group (64 o)
    const int px = blockIdx.x * 256 + threadIdx.x;

    for (int i = threadIdx.x; i < 64 * 72; i += 256)
        kv_l[i] = kvbuf[(size_t)b * 64 * 72 + i];
    __syncthreads();

    float p[64];
#pragma unroll
    for (int i = 0; i < 64; i++) p[i] = 0.f;

    for (int hc = 0; hc < 16; hc++) {
        // ---- attention for 4 heads (channels hc*32 .. hc*32+31) into regs ----
        float att[32];
#pragma unroll
        for (int j = 0; j < 4; j++) {
            const int h = hc * 4 + j;
            const float* buf = (h < 32) ? qkv : agg;
            const int cbase  = (h < 32) ? h * 24 : h * 24 - 768;
            const float* qp = buf + ((size_t)b * 768 + cbase) * HW + px;

            float num[9];
#pragma unroll
            for (int e = 0; e < 9; e++) num[e] = 0.f;
#pragma unroll
            for (int d = 0; d < 8; d++) {
                float qv = fmaxf(qp[(size_t)d * HW], 0.f);
                const float* kvh = &kv_l[h * 72 + d * 9];
#pragma unroll
                for (int e = 0; e < 9; e++) num[e] += qv * kvh[e];
            }
            float rden = 1.f / (num[8] + ATT_EPS);
#pragma unroll
            for (int e = 0; e < 8; e++) att[j * 8 + e] = num[e] * rden;
        }

        // ---- proj partial: p[oo] += w[og*64+oo][hc*32+cc] * att[cc] ----
        const float* wr0 = wproj + (size_t)(og * 64) * 512 + hc * 32; // uniform
#pragma unroll
        for (int oo = 0; oo < 64; oo++) {
            const float* wr = wr0 + oo * 512;   // uniform -> s_load_dwordx16
            float s = p[oo];
#pragma unroll
            for (int cc = 0; cc < 32; cc++) s += wr[cc] * att[cc];
            p[oo] = s;
        }
    }

    const size_t obase = ((size_t)b * 256 + og * 64) * HW + px;
#pragma unroll
    for (int oo = 0; oo < 64; oo++) {
        int o = og * 64 + oo;
        float inv = gamma[o] * rsqrtf(var[o] + BN_EPS);
        float sh  = beta[o] - mean[o] * inv;
        out[obase + (size_t)oo * HW] = x[obase + (size_t)oo * HW] + p[oo] * inv + sh;
    }
}

extern "C" void kernel_launch(void* const* d_in, const int* in_sizes, int n_in,
                              void* d_out, int out_size, void* d_ws, size_t ws_size,
                              hipStream_t stream) {
    const float* x      = (const float*)d_in[0];
    const float* w_qkv  = (const float*)d_in[1];
    const float* w_dw   = (const float*)d_in[2];
    const float* w_pw   = (const float*)d_in[3];
    const float* w_proj = (const float*)d_in[4];
    const float* gamma  = (const float*)d_in[5];
    const float* beta   = (const float*)d_in[6];
    const float* mean   = (const float*)d_in[7];
    const float* var    = (const float*)d_in[8];
    float* out = (float*)d_out;

    float* qkv = (float*)d_ws;                 // 8*768*4096 = 25165824 floats
    float* dwb = qkv + (size_t)25165824;       // depthwise out, then agg in-place
    float* kvb = dwb + (size_t)25165824;       // 8*64*72 floats

    qkv_gemm<<<dim3(4, 48, 8),   256, 0, stream>>>(x, w_qkv, qkv);
    dw_conv <<<dim3(16, 768, 8), 256, 0, stream>>>(qkv, w_dw, dwb);
    agg_pw  <<<dim3(16, 96, 8),  256, 0, stream>>>(dwb, w_pw);
    kv_pass <<<dim3(64, 8),      256, 0, stream>>>(qkv, dwb, kvb);
    att_proj<<<dim3(16, 4, 8),   256, 0, stream>>>(qkv, dwb, kvb, w_proj,
                                                   gamma, beta, mean, var, x, out);
}

// Round 3
// 668.436 us; speedup vs baseline: 1.6875x; 1.6875x over previous
//
#include <hip/hip_runtime.h>
#include <hip/hip_bf16.h>

// LiteMLA: B=8, C=256, H=W=64, N=HW=4096, td=256, d=8, heads=64
// ws: qkv (8,768,4096) | dwb (8,768,4096) | kvb (8,64,72)
// att values are written IN PLACE over the dead v-channel region
// (channels cbase+16..cbase+24 of qkv/dwb) after kv_pass has consumed them.

#define HW 4096
#define ATT_EPS 1e-15f
#define BN_EPS 1e-6f

// ---------------- K1: qkv = w_qkv(768x256) @ x(b,256,4096) ----------------
// grid (4 ntiles, 48 otiles, 8 b), block 256. Thread: 16 o x 4 px (float4).
// Weight tile 16x256 staged in LDS, read as broadcast ds_read_b128.
__global__ __launch_bounds__(256) void qkv_gemm(const float* __restrict__ x,
                                                const float* __restrict__ w,
                                                float* __restrict__ qkv) {
    __shared__ float wl[16 * 256];              // 16 KB
    const int b  = blockIdx.z;
    const int o0 = blockIdx.y * 16;
    const int t  = threadIdx.x;
    const int n4 = blockIdx.x * 256 + t;        // float4 index in [0,1024)

    for (int idx = t; idx < 16 * 256; idx += 256) wl[idx] = w[o0 * 256 + idx];
    __syncthreads();

    const float4* xp = (const float4*)(x + ((size_t)b * 256) * HW) + n4;

    float4 acc[16];
#pragma unroll
    for (int i = 0; i < 16; i++) acc[i] = make_float4(0.f, 0.f, 0.f, 0.f);

    for (int c0 = 0; c0 < 256; c0 += 4) {
        float4 x0 = xp[(c0 + 0) * 1024];
        float4 x1 = xp[(c0 + 1) * 1024];
        float4 x2 = xp[(c0 + 2) * 1024];
        float4 x3 = xp[(c0 + 3) * 1024];
#pragma unroll
        for (int oo = 0; oo < 16; oo++) {
            float4 w4 = *(const float4*)&wl[oo * 256 + c0];   // broadcast b128
            acc[oo].x += w4.x * x0.x + w4.y * x1.x + w4.z * x2.x + w4.w * x3.x;
            acc[oo].y += w4.x * x0.y + w4.y * x1.y + w4.z * x2.y + w4.w * x3.y;
            acc[oo].z += w4.x * x0.z + w4.y * x1.z + w4.z * x2.z + w4.w * x3.z;
            acc[oo].w += w4.x * x0.w + w4.y * x1.w + w4.z * x2.w + w4.w * x3.w;
        }
    }
    float4* po = (float4*)(qkv + ((size_t)b * 768 + o0) * HW) + n4;
#pragma unroll
    for (int oo = 0; oo < 16; oo++) po[oo * 1024] = acc[oo];
}

// ---------------- K2: depthwise 5x5, pad 2 ----------------
__global__ __launch_bounds__(256) void dw_conv(const float* __restrict__ qkv,
                                               const float* __restrict__ wdw,
                                               float* __restrict__ dst) {
    __shared__ float tile[8][64];
    __shared__ float wk[25];
    const int b  = blockIdx.z;
    const int ch = blockIdx.y;
    const int y0 = blockIdx.x * 4;
    const int tx = threadIdx.x & 63;
    const int ty = threadIdx.x >> 6;

    const float* src = qkv + ((size_t)b * 768 + ch) * HW;
    for (int i = threadIdx.x; i < 512; i += 256) {
        int r = i >> 6, xx = i & 63;
        int y = y0 - 2 + r;
        tile[r][xx] = (y >= 0 && y < 64) ? src[y * 64 + xx] : 0.f;
    }
    if (threadIdx.x < 25) wk[threadIdx.x] = wdw[ch * 25 + threadIdx.x];
    __syncthreads();

    float acc = 0.f;
#pragma unroll
    for (int dy = 0; dy < 5; dy++) {
#pragma unroll
        for (int dx = 0; dx < 5; dx++) {
            int xx = tx + dx - 2;
            float v = (xx >= 0 && xx < 64) ? tile[ty + dy][xx] : 0.f;
            acc += wk[dy * 5 + dx] * v;
        }
    }
    dst[((size_t)b * 768 + ch) * HW + (y0 + ty) * 64 + tx] = acc;
}

// ---------------- K3: grouped pointwise 8x8, in place ----------------
__global__ __launch_bounds__(256) void agg_pw(float* __restrict__ buf,
                                              const float* __restrict__ wpw) {
    __shared__ float wl[64];
    const int b = blockIdx.z, g = blockIdx.y;
    const int n = blockIdx.x * 256 + threadIdx.x;
    if (threadIdx.x < 64) wl[threadIdx.x] = wpw[g * 64 + threadIdx.x];
    __syncthreads();

    float* base = buf + ((size_t)b * 768 + g * 8) * HW + n;
    float d[8];
#pragma unroll
    for (int i = 0; i < 8; i++) d[i] = base[(size_t)i * HW];
#pragma unroll
    for (int o = 0; o < 8; o++) {
        float acc = 0.f;
#pragma unroll
        for (int i = 0; i < 8; i++) acc += wl[o * 8 + i] * d[i];
        base[(size_t)o * HW] = acc;
    }
}

// ---------------- K4: kv[d][e] = sum_n relu(k[n,d]) * vpad[n,e] ----------------
// grid (64 h, 8 b), block 256, float4 loads.
__global__ __launch_bounds__(256) void kv_pass(const float* __restrict__ qkv,
                                               const float* __restrict__ agg,
                                               float* __restrict__ kvout) {
    const int h = blockIdx.x, b = blockIdx.y;
    const float* buf = (h < 32) ? qkv : agg;
    const int cbase  = (h < 32) ? h * 24 : (h - 32) * 24;
    const float4* kp4 = (const float4*)(buf + ((size_t)b * 768 + cbase + 8)  * HW);
    const float4* vp4 = (const float4*)(buf + ((size_t)b * 768 + cbase + 16) * HW);

    float acc[8][9];
#pragma unroll
    for (int d = 0; d < 8; d++)
#pragma unroll
        for (int e = 0; e < 9; e++) acc[d][e] = 0.f;

#pragma unroll
    for (int k = 0; k < 4; k++) {
        const int nn = threadIdx.x + k * 256;
        float4 kk[8];
#pragma unroll
        for (int d = 0; d < 8; d++) {
            float4 v = kp4[d * 1024 + nn];
            kk[d].x = fmaxf(v.x, 0.f); kk[d].y = fmaxf(v.y, 0.f);
            kk[d].z = fmaxf(v.z, 0.f); kk[d].w = fmaxf(v.w, 0.f);
        }
#pragma unroll
        for (int e = 0; e < 8; e++) {
            float4 vv = vp4[e * 1024 + nn];
#pragma unroll
            for (int d = 0; d < 8; d++)
                acc[d][e] += kk[d].x * vv.x + kk[d].y * vv.y +
                             kk[d].z * vv.z + kk[d].w * vv.w;
        }
#pragma unroll
        for (int d = 0; d < 8; d++)
            acc[d][8] += kk[d].x + kk[d].y + kk[d].z + kk[d].w;
    }

    __shared__ float red[4][72];
    const int lane = threadIdx.x & 63, wv = threadIdx.x >> 6;
#pragma unroll
    for (int d = 0; d < 8; d++) {
#pragma unroll
        for (int e = 0; e < 9; e++) {
            float v = acc[d][e];
            v += __shfl_xor(v, 1);  v += __shfl_xor(v, 2);
            v += __shfl_xor(v, 4);  v += __shfl_xor(v, 8);
            v += __shfl_xor(v, 16); v += __shfl_xor(v, 32);
            if (lane == 0) red[wv][d * 9 + e] = v;
        }
    }
    __syncthreads();
    if (threadIdx.x < 72) {
        float s = red[0][threadIdx.x] + red[1][threadIdx.x] +
                  red[2][threadIdx.x] + red[3][threadIdx.x];
        kvout[((size_t)(b * 64 + h)) * 72 + threadIdx.x] = s;
    }
}

// ---------------- K5: att = (relu(q)@kv)/den, written over v channels ----------------
// grid (4 pxtiles, 64 h, 8 b), block 256, 4 px per thread.
__global__ __launch_bounds__(256) void att_pass(float* __restrict__ qkv,
                                                float* __restrict__ agg,
                                                const float* __restrict__ kvbuf) {
    __shared__ float kvl[72];
    const int h = blockIdx.y, b = blockIdx.z;
    const int t = threadIdx.x;
    if (t < 72) kvl[t] = kvbuf[((size_t)(b * 64 + h)) * 72 + t];
    __syncthreads();

    float* buf = (h < 32) ? qkv : agg;
    const int cbase = (h < 32) ? h * 24 : (h - 32) * 24;
    const int n4 = blockIdx.x * 256 + t;
    const float4* qp = (const float4*)(buf + ((size_t)b * 768 + cbase) * HW) + n4;
    float4*       op = (float4*)(buf + ((size_t)b * 768 + cbase + 16) * HW) + n4;

    float4 num[9];
#pragma unroll
    for (int e = 0; e < 9; e++) num[e] = make_float4(0.f, 0.f, 0.f, 0.f);

#pragma unroll
    for (int d = 0; d < 8; d++) {
        float4 q = qp[d * 1024];
        q.x = fmaxf(q.x, 0.f); q.y = fmaxf(q.y, 0.f);
        q.z = fmaxf(q.z, 0.f); q.w = fmaxf(q.w, 0.f);
#pragma unroll
        for (int e = 0; e < 9; e++) {
            float kvv = kvl[d * 9 + e];
            num[e].x += kvv * q.x; num[e].y += kvv * q.y;
            num[e].z += kvv * q.z; num[e].w += kvv * q.w;
        }
    }
    float4 rd;
    rd.x = 1.f / (num[8].x + ATT_EPS); rd.y = 1.f / (num[8].y + ATT_EPS);
    rd.z = 1.f / (num[8].z + ATT_EPS); rd.w = 1.f / (num[8].w + ATT_EPS);
#pragma unroll
    for (int e = 0; e < 8; e++) {
        float4 o;
        o.x = num[e].x * rd.x; o.y = num[e].y * rd.y;
        o.z = num[e].z * rd.z; o.w = num[e].w * rd.w;
        op[e * 1024] = o;
    }
}

// ---------------- K6: p = w_proj(256x512) @ att, BN, +x ----------------
// grid (4 ntiles, 16 otiles, 8 b), block 256. Thread: 16 o x 4 px.
// att channel c = h*8+e lives at physical channel (h%32)*24+16+e of qkv/agg.
__global__ __launch_bounds__(256) void proj_gemm(const float* __restrict__ qkv,
                                                 const float* __restrict__ agg,
                                                 const float* __restrict__ wproj,
                                                 const float* __restrict__ gamma,
                                                 const float* __restrict__ beta,
                                                 const float* __restrict__ mean,
                                                 const float* __restrict__ var,
                                                 const float* __restrict__ x,
                                                 float* __restrict__ out) {
    __shared__ float wl[16 * 512];              // 32 KB
    const int b  = blockIdx.z;
    const int o0 = blockIdx.y * 16;
    const int t  = threadIdx.x;
    const int n4 = blockIdx.x * 256 + t;

    for (int idx = t; idx < 16 * 512; idx += 256) wl[idx] = wproj[o0 * 512 + idx];
    __syncthreads();

    float4 acc[16];
#pragma unroll
    for (int i = 0; i < 16; i++) acc[i] = make_float4(0.f, 0.f, 0.f, 0.f);

    for (int hh = 0; hh < 64; hh++) {
        const float* ab = ((hh < 32) ? qkv : agg) +
                          ((size_t)b * 768 + (hh & 31) * 24 + 16) * HW;
        const float4* ap = (const float4*)ab + n4;
#pragma unroll
        for (int half = 0; half < 2; half++) {
            const int c0 = hh * 8 + half * 4;
            float4 x0 = ap[(half * 4 + 0) * 1024];
            float4 x1 = ap[(half * 4 + 1) * 1024];
            float4 x2 = ap[(half * 4 + 2) * 1024];
            float4 x3 = ap[(half * 4 + 3) * 1024];
#pragma unroll
            for (int oo = 0; oo < 16; oo++) {
                float4 w4 = *(const float4*)&wl[oo * 512 + c0];
                acc[oo].x += w4.x * x0.x + w4.y * x1.x + w4.z * x2.x + w4.w * x3.x;
                acc[oo].y += w4.x * x0.y + w4.y * x1.y + w4.z * x2.y + w4.w * x3.y;
                acc[oo].z += w4.x * x0.z + w4.y * x1.z + w4.z * x2.z + w4.w * x3.z;
                acc[oo].w += w4.x * x0.w + w4.y * x1.w + w4.z * x2.w + w4.w * x3.w;
            }
        }
    }

#pragma unroll
    for (int oo = 0; oo < 16; oo++) {
        const int o = o0 + oo;
        float inv = gamma[o] * rsqrtf(var[o] + BN_EPS);
        float sh  = beta[o] - mean[o] * inv;
        float4 xr = ((const float4*)(x + ((size_t)b * 256 + o) * HW))[n4];
        float4 r;
        r.x = xr.x + acc[oo].x * inv + sh;
        r.y = xr.y + acc[oo].y * inv + sh;
        r.z = xr.z + acc[oo].z * inv + sh;
        r.w = xr.w + acc[oo].w * inv + sh;
        ((float4*)(out + ((size_t)b * 256 + o) * HW))[n4] = r;
    }
}

extern "C" void kernel_launch(void* const* d_in, const int* in_sizes, int n_in,
                              void* d_out, int out_size, void* d_ws, size_t ws_size,
                              hipStream_t stream) {
    const float* x      = (const float*)d_in[0];
    const float* w_qkv  = (const float*)d_in[1];
    const float* w_dw   = (const float*)d_in[2];
    const float* w_pw   = (const float*)d_in[3];
    const float* w_proj = (const float*)d_in[4];
    const float* gamma  = (const float*)d_in[5];
    const float* beta   = (const float*)d_in[6];
    const float* mean   = (const float*)d_in[7];
    const float* var    = (const float*)d_in[8];
    float* out = (float*)d_out;

    float* qkv = (float*)d_ws;                 // 25165824 floats
    float* dwb = qkv + (size_t)25165824;       // dw out, then agg in-place, then att
    float* kvb = dwb + (size_t)25165824;       // 8*64*72 floats

    qkv_gemm <<<dim3(4, 48, 8),   256, 0, stream>>>(x, w_qkv, qkv);
    dw_conv  <<<dim3(16, 768, 8), 256, 0, stream>>>(qkv, w_dw, dwb);
    agg_pw   <<<dim3(16, 96, 8),  256, 0, stream>>>(dwb, w_pw);
    kv_pass  <<<dim3(64, 8),      256, 0, stream>>>(qkv, dwb, kvb);
    att_pass <<<dim3(4, 64, 8),   256, 0, stream>>>(qkv, dwb, kvb);
    proj_gemm<<<dim3(4, 16, 8),   256, 0, stream>>>(qkv, dwb, w_proj,
                                                    gamma, beta, mean, var, x, out);
}

// Round 4
// 365.418 us; speedup vs baseline: 3.0868x; 1.8292x over previous
//
#include <hip/hip_runtime.h>
#include <hip/hip_bf16.h>

// LiteMLA: B=8, C=256, H=W=64, N=HW=4096, td=256, d=8, heads=64
// ws: qkv (8,768,4096) f32 | dwb (8,768,4096) f32 | kvb (8,64,72) f32
// att values written IN PLACE over the dead v-channel region (fp32).

#define HW 4096
#define ATT_EPS 1e-15f
#define BN_EPS 1e-6f

typedef __attribute__((ext_vector_type(8))) short short8;
typedef __attribute__((ext_vector_type(4))) short short4v;
typedef __attribute__((ext_vector_type(4))) float f32x4;

static __device__ inline short f2bf(float f) {
    union { float f; unsigned u; } v; v.f = f;
    unsigned r = v.u + 0x7fff + ((v.u >> 16) & 1);   // RNE, finite inputs
    return (short)(r >> 16);
}

// ---------------- K1: qkv = W(768x256) @ X(256x4096) per batch, bf16 MFMA ----
// grid (32 nb, 6 ob, 8 b), block 256 = 4 waves (2x2). Block tile 128o x 128n.
// LDS: A_l[128][40] bf16 (row=o,k-contig), B_l[128][40] bf16 (row=n,k-contig).
__global__ __launch_bounds__(256) void qkv_gemm(const float* __restrict__ x,
                                                const float* __restrict__ w,
                                                float* __restrict__ qkv) {
    __shared__ short A_l[128 * 40];
    __shared__ short B_l[128 * 40];
    const int t  = threadIdx.x;
    const int b  = blockIdx.z;
    const int ob = blockIdx.y * 128;
    const int nb = blockIdx.x * 128;
    const float* xb = x + (size_t)b * 256 * HW;

    const int lane = t & 63, wave = t >> 6;
    const int wo = (wave >> 1) * 64, wn = (wave & 1) * 64;

    f32x4 acc[4][4];
#pragma unroll
    for (int s = 0; s < 4; s++)
#pragma unroll
        for (int u = 0; u < 4; u++) acc[s][u] = (f32x4){0.f, 0.f, 0.f, 0.f};

    const int col4 = (t & 7) * 4;       // k-offset (floats) for A staging
    const int r0   = t >> 3;            // 0..31
    for (int kb = 0; kb < 256; kb += 32) {
        __syncthreads();
        // stage A: W[ob..+127][kb..+31]
#pragma unroll
        for (int i = 0; i < 4; i++) {
            const int r = r0 + 32 * i;
            float4 v = *(const float4*)&w[(ob + r) * 256 + kb + col4];
            short4v s4 = {f2bf(v.x), f2bf(v.y), f2bf(v.z), f2bf(v.w)};
            *(short4v*)&A_l[r * 40 + col4] = s4;
        }
        // stage B transposed: X[kb+c][nb + n..] -> B_l[n][c]
#pragma unroll
        for (int i = 0; i < 4; i++) {
            const int n4 = (t & 7) + 8 * i;
            float4 v = *(const float4*)&xb[(size_t)(kb + r0) * HW + nb + n4 * 4];
            B_l[(n4 * 4 + 0) * 40 + r0] = f2bf(v.x);
            B_l[(n4 * 4 + 1) * 40 + r0] = f2bf(v.y);
            B_l[(n4 * 4 + 2) * 40 + r0] = f2bf(v.z);
            B_l[(n4 * 4 + 3) * 40 + r0] = f2bf(v.w);
        }
        __syncthreads();

        short8 af[4], bf[4];
#pragma unroll
        for (int s = 0; s < 4; s++)
            af[s] = *(const short8*)&A_l[(wo + s * 16 + (lane & 15)) * 40 + (lane >> 4) * 8];
#pragma unroll
        for (int u = 0; u < 4; u++)
            bf[u] = *(const short8*)&B_l[(wn + u * 16 + (lane & 15)) * 40 + (lane >> 4) * 8];
#pragma unroll
        for (int s = 0; s < 4; s++)
#pragma unroll
            for (int u = 0; u < 4; u++)
                acc[s][u] = __builtin_amdgcn_mfma_f32_16x16x32_bf16(af[s], bf[u], acc[s][u], 0, 0, 0);
    }

#pragma unroll
    for (int s = 0; s < 4; s++)
#pragma unroll
        for (int u = 0; u < 4; u++)
#pragma unroll
            for (int r = 0; r < 4; r++) {
                const int o = ob + wo + s * 16 + (lane >> 4) * 4 + r;
                const int n = nb + wn + u * 16 + (lane & 15);
                qkv[((size_t)b * 768 + o) * HW + n] = acc[s][u][r];
            }
}

// ---------------- K2: depthwise 5x5, pad 2 ----------------
__global__ __launch_bounds__(256) void dw_conv(const float* __restrict__ qkv,
                                               const float* __restrict__ wdw,
                                               float* __restrict__ dst) {
    __shared__ float tile[8][64];
    __shared__ float wk[25];
    const int b  = blockIdx.z;
    const int ch = blockIdx.y;
    const int y0 = blockIdx.x * 4;
    const int tx = threadIdx.x & 63;
    const int ty = threadIdx.x >> 6;

    const float* src = qkv + ((size_t)b * 768 + ch) * HW;
    for (int i = threadIdx.x; i < 512; i += 256) {
        int r = i >> 6, xx = i & 63;
        int y = y0 - 2 + r;
        tile[r][xx] = (y >= 0 && y < 64) ? src[y * 64 + xx] : 0.f;
    }
    if (threadIdx.x < 25) wk[threadIdx.x] = wdw[ch * 25 + threadIdx.x];
    __syncthreads();

    float acc = 0.f;
#pragma unroll
    for (int dy = 0; dy < 5; dy++) {
#pragma unroll
        for (int dx = 0; dx < 5; dx++) {
            int xx = tx + dx - 2;
            float v = (xx >= 0 && xx < 64) ? tile[ty + dy][xx] : 0.f;
            acc += wk[dy * 5 + dx] * v;
        }
    }
    dst[((size_t)b * 768 + ch) * HW + (y0 + ty) * 64 + tx] = acc;
}

// ---------------- K3: grouped pointwise 8x8, in place ----------------
__global__ __launch_bounds__(256) void agg_pw(float* __restrict__ buf,
                                              const float* __restrict__ wpw) {
    __shared__ float wl[64];
    const int b = blockIdx.z, g = blockIdx.y;
    const int n = blockIdx.x * 256 + threadIdx.x;
    if (threadIdx.x < 64) wl[threadIdx.x] = wpw[g * 64 + threadIdx.x];
    __syncthreads();

    float* base = buf + ((size_t)b * 768 + g * 8) * HW + n;
    float d[8];
#pragma unroll
    for (int i = 0; i < 8; i++) d[i] = base[(size_t)i * HW];
#pragma unroll
    for (int o = 0; o < 8; o++) {
        float acc = 0.f;
#pragma unroll
        for (int i = 0; i < 8; i++) acc += wl[o * 8 + i] * d[i];
        base[(size_t)o * HW] = acc;
    }
}

// ---------------- K4: kv[d][e] = sum_n relu(k[n,d]) * vpad[n,e] ----------------
__global__ __launch_bounds__(256) void kv_pass(const float* __restrict__ qkv,
                                               const float* __restrict__ agg,
                                               float* __restrict__ kvout) {
    const int h = blockIdx.x, b = blockIdx.y;
    const float* buf = (h < 32) ? qkv : agg;
    const int cbase  = (h < 32) ? h * 24 : (h - 32) * 24;
    const float4* kp4 = (const float4*)(buf + ((size_t)b * 768 + cbase + 8)  * HW);
    const float4* vp4 = (const float4*)(buf + ((size_t)b * 768 + cbase + 16) * HW);

    float acc[8][9];
#pragma unroll
    for (int d = 0; d < 8; d++)
#pragma unroll
        for (int e = 0; e < 9; e++) acc[d][e] = 0.f;

#pragma unroll
    for (int k = 0; k < 4; k++) {
        const int nn = threadIdx.x + k * 256;
        float4 kk[8];
#pragma unroll
        for (int d = 0; d < 8; d++) {
            float4 v = kp4[d * 1024 + nn];
            kk[d].x = fmaxf(v.x, 0.f); kk[d].y = fmaxf(v.y, 0.f);
            kk[d].z = fmaxf(v.z, 0.f); kk[d].w = fmaxf(v.w, 0.f);
        }
#pragma unroll
        for (int e = 0; e < 8; e++) {
            float4 vv = vp4[e * 1024 + nn];
#pragma unroll
            for (int d = 0; d < 8; d++)
                acc[d][e] += kk[d].x * vv.x + kk[d].y * vv.y +
                             kk[d].z * vv.z + kk[d].w * vv.w;
        }
#pragma unroll
        for (int d = 0; d < 8; d++)
            acc[d][8] += kk[d].x + kk[d].y + kk[d].z + kk[d].w;
    }

    __shared__ float red[4][72];
    const int lane = threadIdx.x & 63, wv = threadIdx.x >> 6;
#pragma unroll
    for (int d = 0; d < 8; d++) {
#pragma unroll
        for (int e = 0; e < 9; e++) {
            float v = acc[d][e];
            v += __shfl_xor(v, 1);  v += __shfl_xor(v, 2);
            v += __shfl_xor(v, 4);  v += __shfl_xor(v, 8);
            v += __shfl_xor(v, 16); v += __shfl_xor(v, 32);
            if (lane == 0) red[wv][d * 9 + e] = v;
        }
    }
    __syncthreads();
    if (threadIdx.x < 72) {
        float s = red[0][threadIdx.x] + red[1][threadIdx.x] +
                  red[2][threadIdx.x] + red[3][threadIdx.x];
        kvout[((size_t)(b * 64 + h)) * 72 + threadIdx.x] = s;
    }
}

// ---------------- K5: att = (relu(q)@kv)/den, over v channels (fp32) ----------
__global__ __launch_bounds__(256) void att_pass(float* __restrict__ qkv,
                                                float* __restrict__ agg,
                                                const float* __restrict__ kvbuf) {
    __shared__ float kvl[72];
    const int h = blockIdx.y, b = blockIdx.z;
    const int t = threadIdx.x;
    if (t < 72) kvl[t] = kvbuf[((size_t)(b * 64 + h)) * 72 + t];
    __syncthreads();

    float* buf = (h < 32) ? qkv : agg;
    const int cbase = (h < 32) ? h * 24 : (h - 32) * 24;
    const int n4 = blockIdx.x * 256 + t;
    const float4* qp = (const float4*)(buf + ((size_t)b * 768 + cbase) * HW) + n4;
    float4*       op = (float4*)(buf + ((size_t)b * 768 + cbase + 16) * HW) + n4;

    float4 num[9];
#pragma unroll
    for (int e = 0; e < 9; e++) num[e] = make_float4(0.f, 0.f, 0.f, 0.f);

#pragma unroll
    for (int d = 0; d < 8; d++) {
        float4 q = qp[d * 1024];
        q.x = fmaxf(q.x, 0.f); q.y = fmaxf(q.y, 0.f);
        q.z = fmaxf(q.z, 0.f); q.w = fmaxf(q.w, 0.f);
#pragma unroll
        for (int e = 0; e < 9; e++) {
            float kvv = kvl[d * 9 + e];
            num[e].x += kvv * q.x; num[e].y += kvv * q.y;
            num[e].z += kvv * q.z; num[e].w += kvv * q.w;
        }
    }
    float4 rd;
    rd.x = 1.f / (num[8].x + ATT_EPS); rd.y = 1.f / (num[8].y + ATT_EPS);
    rd.z = 1.f / (num[8].z + ATT_EPS); rd.w = 1.f / (num[8].w + ATT_EPS);
#pragma unroll
    for (int e = 0; e < 8; e++) {
        float4 o;
        o.x = num[e].x * rd.x; o.y = num[e].y * rd.y;
        o.z = num[e].z * rd.z; o.w = num[e].w * rd.w;
        op[e * 1024] = o;
    }
}

// ---------------- K6: p = Wp(256x512) @ att, BN, +x — bf16 MFMA -------------
// grid (32 nb, 2 ob, 8 b), block 256 = 4 waves (2x2). Tile 128o x 128n, K=512.
// att channel c = h*8+e lives at physical channel (h&31)*24+16+e of qkv/agg.
__global__ __launch_bounds__(256) void proj_gemm(const float* __restrict__ qkv,
                                                 const float* __restrict__ agg,
                                                 const float* __restrict__ wproj,
                                                 const float* __restrict__ gamma,
                                                 const float* __restrict__ beta,
                                                 const float* __restrict__ mean,
                                                 const float* __restrict__ var,
                                                 const float* __restrict__ x,
                                                 float* __restrict__ out) {
    __shared__ short A_l[128 * 40];
    __shared__ short B_l[128 * 40];
    __shared__ float inv_l[128], sh_l[128];
    const int t  = threadIdx.x;
    const int b  = blockIdx.z;
    const int ob = blockIdx.y * 128;
    const int nb = blockIdx.x * 128;

    if (t < 128) {
        const int o = ob + t;
        float iv = gamma[o] * rsqrtf(var[o] + BN_EPS);
        inv_l[t] = iv;
        sh_l[t]  = beta[o] - mean[o] * iv;
    }

    const int lane = t & 63, wave = t >> 6;
    const int wo = (wave >> 1) * 64, wn = (wave & 1) * 64;

    f32x4 acc[4][4];
#pragma unroll
    for (int s = 0; s < 4; s++)
#pragma unroll
        for (int u = 0; u < 4; u++) acc[s][u] = (f32x4){0.f, 0.f, 0.f, 0.f};

    const int col4 = (t & 7) * 4;
    const int r0   = t >> 3;            // 0..31
    for (int kb = 0; kb < 512; kb += 32) {
        __syncthreads();
#pragma unroll
        for (int i = 0; i < 4; i++) {
            const int r = r0 + 32 * i;
            float4 v = *(const float4*)&wproj[(ob + r) * 512 + kb + col4];
            short4v s4 = {f2bf(v.x), f2bf(v.y), f2bf(v.z), f2bf(v.w)};
            *(short4v*)&A_l[r * 40 + col4] = s4;
        }
        // B: att channel c_glob = kb + r0
        {
            const int cg = kb + r0;
            const int h = cg >> 3, e = cg & 7;
            const float* ap = ((h < 32) ? qkv : agg) +
                              ((size_t)b * 768 + (h & 31) * 24 + 16 + e) * HW + nb;
#pragma unroll
            for (int i = 0; i < 4; i++) {
                const int n4 = (t & 7) + 8 * i;
                float4 v = *(const float4*)&ap[n4 * 4];
                B_l[(n4 * 4 + 0) * 40 + r0] = f2bf(v.x);
                B_l[(n4 * 4 + 1) * 40 + r0] = f2bf(v.y);
                B_l[(n4 * 4 + 2) * 40 + r0] = f2bf(v.z);
                B_l[(n4 * 4 + 3) * 40 + r0] = f2bf(v.w);
            }
        }
        __syncthreads();

        short8 af[4], bf[4];
#pragma unroll
        for (int s = 0; s < 4; s++)
            af[s] = *(const short8*)&A_l[(wo + s * 16 + (lane & 15)) * 40 + (lane >> 4) * 8];
#pragma unroll
        for (int u = 0; u < 4; u++)
            bf[u] = *(const short8*)&B_l[(wn + u * 16 + (lane & 15)) * 40 + (lane >> 4) * 8];
#pragma unroll
        for (int s = 0; s < 4; s++)
#pragma unroll
            for (int u = 0; u < 4; u++)
                acc[s][u] = __builtin_amdgcn_mfma_f32_16x16x32_bf16(af[s], bf[u], acc[s][u], 0, 0, 0);
    }

#pragma unroll
    for (int s = 0; s < 4; s++)
#pragma unroll
        for (int u = 0; u < 4; u++)
#pragma unroll
            for (int r = 0; r < 4; r++) {
                const int ol = wo + s * 16 + (lane >> 4) * 4 + r;
                const int n  = nb + wn + u * 16 + (lane & 15);
                const size_t idx = ((size_t)b * 256 + ob + ol) * HW + n;
                out[idx] = x[idx] + acc[s][u][r] * inv_l[ol] + sh_l[ol];
            }
}

extern "C" void kernel_launch(void* const* d_in, const int* in_sizes, int n_in,
                              void* d_out, int out_size, void* d_ws, size_t ws_size,
                              hipStream_t stream) {
    const float* x      = (const float*)d_in[0];
    const float* w_qkv  = (const float*)d_in[1];
    const float* w_dw   = (const float*)d_in[2];
    const float* w_pw   = (const float*)d_in[3];
    const float* w_proj = (const float*)d_in[4];
    const float* gamma  = (const float*)d_in[5];
    const float* beta   = (const float*)d_in[6];
    const float* mean   = (const float*)d_in[7];
    const float* var    = (const float*)d_in[8];
    float* out = (float*)d_out;

    float* qkv = (float*)d_ws;                 // 25165824 floats
    float* dwb = qkv + (size_t)25165824;       // dw out, then agg in-place, then att
    float* kvb = dwb + (size_t)25165824;       // 8*64*72 floats

    qkv_gemm <<<dim3(32, 6, 8),   256, 0, stream>>>(x, w_qkv, qkv);
    dw_conv  <<<dim3(16, 768, 8), 256, 0, stream>>>(qkv, w_dw, dwb);
    agg_pw   <<<dim3(16, 96, 8),  256, 0, stream>>>(dwb, w_pw);
    kv_pass  <<<dim3(64, 8),      256, 0, stream>>>(qkv, dwb, kvb);
    att_pass <<<dim3(4, 64, 8),   256, 0, stream>>>(qkv, dwb, kvb);
    proj_gemm<<<dim3(32, 2, 8),   256, 0, stream>>>(qkv, dwb, w_proj,
                                                    gamma, beta, mean, var, x, out);
}

// Round 6
// 308.402 us; speedup vs baseline: 3.6574x; 1.1849x over previous
//
#include <hip/hip_runtime.h>
#include <hip/hip_bf16.h>

// LiteMLA: B=8, C=256, H=W=64, N=HW=4096, td=256, d=8, heads=64
// ws: qkv bf16 (8,768,4096) | agg bf16 (8,768,4096) | kvb f32 (8,64,72)
// Pipeline: qkv_gemm (MFMA) -> dw_agg (fused dw5x5 + grouped pw8x8)
//        -> kv_pass -> proj_att (fused attention + proj MFMA + BN + residual)

#define HW 4096
#define ATT_EPS 1e-15f
#define BN_EPS 1e-6f

typedef __attribute__((ext_vector_type(8))) short short8;
typedef __attribute__((ext_vector_type(4))) short short4v;
typedef __attribute__((ext_vector_type(4))) float f32x4;
typedef __attribute__((ext_vector_type(8))) unsigned short u16x8;
typedef __attribute__((ext_vector_type(4))) unsigned short u16x4;

static __device__ inline short f2bf(float f) {
    union { float f; unsigned u; } v; v.f = f;
    unsigned r = v.u + 0x7fff + ((v.u >> 16) & 1);   // RNE, finite inputs
    return (short)(r >> 16);
}
static __device__ inline float bf2f(unsigned short u) {
    union { unsigned u; float f; } v; v.u = (unsigned)u << 16; return v.f;
}

// ---------------- K1: qkv(bf16) = W(768x256) @ X(256x4096), bf16 MFMA --------
// grid (32 nb, 6 ob, 8 b), block 256 = 4 waves (2x2). Tile 128o x 128n, BK=32.
__global__ __launch_bounds__(256) void qkv_gemm(const float* __restrict__ x,
                                                const float* __restrict__ w,
                                                unsigned short* __restrict__ qkv) {
    __shared__ short A_l[128 * 40];
    __shared__ short B_l[128 * 40];
    const int t  = threadIdx.x;
    const int b  = blockIdx.z;
    const int ob = blockIdx.y * 128;
    const int nb = blockIdx.x * 128;
    const float* xb = x + (size_t)b * 256 * HW;

    const int lane = t & 63, wave = t >> 6;
    const int wo = (wave >> 1) * 64, wn = (wave & 1) * 64;

    f32x4 acc[4][4];
#pragma unroll
    for (int s = 0; s < 4; s++)
#pragma unroll
        for (int u = 0; u < 4; u++) acc[s][u] = (f32x4){0.f, 0.f, 0.f, 0.f};

    const int col4 = (t & 7) * 4;
    const int r0   = t >> 3;            // 0..31
    for (int kb = 0; kb < 256; kb += 32) {
        __syncthreads();
#pragma unroll
        for (int i = 0; i < 4; i++) {
            const int r = r0 + 32 * i;
            float4 v = *(const float4*)&w[(ob + r) * 256 + kb + col4];
            short4v s4 = {f2bf(v.x), f2bf(v.y), f2bf(v.z), f2bf(v.w)};
            *(short4v*)&A_l[r * 40 + col4] = s4;
        }
#pragma unroll
        for (int i = 0; i < 4; i++) {
            const int n4 = (t & 7) + 8 * i;
            float4 v = *(const float4*)&xb[(size_t)(kb + r0) * HW + nb + n4 * 4];
            B_l[(n4 * 4 + 0) * 40 + r0] = f2bf(v.x);
            B_l[(n4 * 4 + 1) * 40 + r0] = f2bf(v.y);
            B_l[(n4 * 4 + 2) * 40 + r0] = f2bf(v.z);
            B_l[(n4 * 4 + 3) * 40 + r0] = f2bf(v.w);
        }
        __syncthreads();

        short8 af[4], bf[4];
#pragma unroll
        for (int s = 0; s < 4; s++)
            af[s] = *(const short8*)&A_l[(wo + s * 16 + (lane & 15)) * 40 + (lane >> 4) * 8];
#pragma unroll
        for (int u = 0; u < 4; u++)
            bf[u] = *(const short8*)&B_l[(wn + u * 16 + (lane & 15)) * 40 + (lane >> 4) * 8];
#pragma unroll
        for (int s = 0; s < 4; s++)
#pragma unroll
            for (int u = 0; u < 4; u++)
                acc[s][u] = __builtin_amdgcn_mfma_f32_16x16x32_bf16(af[s], bf[u], acc[s][u], 0, 0, 0);
    }

#pragma unroll
    for (int s = 0; s < 4; s++)
#pragma unroll
        for (int u = 0; u < 4; u++)
#pragma unroll
            for (int r = 0; r < 4; r++) {
                const int o = ob + wo + s * 16 + (lane >> 4) * 4 + r;
                const int n = nb + wn + u * 16 + (lane & 15);
                qkv[((size_t)b * 768 + o) * HW + n] = (unsigned short)f2bf(acc[s][u][r]);
            }
}

// ---------------- K2: fused depthwise 5x5 + grouped pointwise 8x8 ------------
// grid (4 ytiles(16 rows), 96 g, 8 b), block 256. Thread: 1 row x 4 col x 8 ch.
// LDS input tile fp32, zero-padded (cols +-2, halo rows) -> no bounds checks.
__global__ __launch_bounds__(256) void dw_agg(const unsigned short* __restrict__ qkv,
                                              const float* __restrict__ wdw,
                                              const float* __restrict__ wpw,
                                              unsigned short* __restrict__ agg) {
    __shared__ float in_t[8][20][68];   // 43.5 KB
    __shared__ float wk[8][25];
    __shared__ float pw[64];
    const int b = blockIdx.z, g = blockIdx.y;
    const int y0 = blockIdx.x * 16;
    const int t = threadIdx.x;

    // zero the tile (covers col pads + out-of-range halo rows)
    float4* zp = (float4*)in_t;
    for (int i = t; i < 8 * 20 * 68 / 4; i += 256) zp[i] = make_float4(0.f, 0.f, 0.f, 0.f);
    if (t < 200) wk[t / 25][t % 25] = wdw[(g * 8) * 25 + t];  // 8 ch x 25 taps
    if (t < 64)  pw[t] = wpw[g * 64 + t];                     // full 8x8 pw tile
    __syncthreads();

    // load valid rows: 8 ch x 20 r x 8 col-groups of 8 shorts = 1280 items
    for (int i = t; i < 1280; i += 256) {
        const int ch = i / 160, rem = i % 160;
        const int r = rem >> 3, c8 = rem & 7;
        const int y = y0 - 2 + r;
        if (y >= 0 && y < 64) {
            const unsigned short* src =
                qkv + ((size_t)(b * 768 + g * 8 + ch)) * HW + y * 64 + c8 * 8;
            u16x8 v = *(const u16x8*)src;
            float* dp = &in_t[ch][r][2 + c8 * 8];
#pragma unroll
            for (int j = 0; j < 8; j++) dp[j] = bf2f(v[j]);
        }
    }
    __syncthreads();

    const int tx = t & 15, ty = t >> 4;     // col group, output row
    float dwres[8][4];
#pragma unroll
    for (int ch = 0; ch < 8; ch++) {
        float a0 = 0.f, a1 = 0.f, a2 = 0.f, a3 = 0.f;
#pragma unroll
        for (int dy = 0; dy < 5; dy++) {
            const float* rp = &in_t[ch][ty + dy][tx * 4];
            float4 f0 = *(const float4*)rp;
            float4 f1 = *(const float4*)(rp + 4);
            float win[8] = {f0.x, f0.y, f0.z, f0.w, f1.x, f1.y, f1.z, f1.w};
#pragma unroll
            for (int dx = 0; dx < 5; dx++) {
                const float wv = wk[ch][dy * 5 + dx];
                a0 += wv * win[dx + 0];
                a1 += wv * win[dx + 1];
                a2 += wv * win[dx + 2];
                a3 += wv * win[dx + 3];
            }
        }
        dwres[ch][0] = a0; dwres[ch][1] = a1; dwres[ch][2] = a2; dwres[ch][3] = a3;
    }
#pragma unroll
    for (int o = 0; o < 8; o++) {
        float s0 = 0.f, s1 = 0.f, s2 = 0.f, s3 = 0.f;
#pragma unroll
        for (int i = 0; i < 8; i++) {
            const float wv = pw[o * 8 + i];
            s0 += wv * dwres[i][0]; s1 += wv * dwres[i][1];
            s2 += wv * dwres[i][2]; s3 += wv * dwres[i][3];
        }
        u16x4 rv = {(unsigned short)f2bf(s0), (unsigned short)f2bf(s1),
                    (unsigned short)f2bf(s2), (unsigned short)f2bf(s3)};
        *(u16x4*)&agg[((size_t)(b * 768 + g * 8 + o)) * HW + (y0 + ty) * 64 + tx * 4] = rv;
    }
}

// ---------------- K3: kv[d][e] = sum_n relu(k[n,d]) * vpad[n,e], bf16 in -----
__global__ __launch_bounds__(256) void kv_pass(const unsigned short* __restrict__ qkv,
                                               const unsigned short* __restrict__ agg,
                                               float* __restrict__ kvout) {
    const int h = blockIdx.x, b = blockIdx.y;
    const unsigned short* buf = (h < 32) ? qkv : agg;
    const int cbase = (h < 32) ? h * 24 : (h - 32) * 24;
    const u16x4* kp4 = (const u16x4*)(buf + ((size_t)b * 768 + cbase + 8)  * HW);
    const u16x4* vp4 = (const u16x4*)(buf + ((size_t)b * 768 + cbase + 16) * HW);

    float acc[8][9];
#pragma unroll
    for (int d = 0; d < 8; d++)
#pragma unroll
        for (int e = 0; e < 9; e++) acc[d][e] = 0.f;

#pragma unroll
    for (int k = 0; k < 4; k++) {
        const int nn = threadIdx.x + k * 256;
        float kk[8][4];
#pragma unroll
        for (int d = 0; d < 8; d++) {
            u16x4 v = kp4[d * 1024 + nn];
            kk[d][0] = fmaxf(bf2f(v.x), 0.f); kk[d][1] = fmaxf(bf2f(v.y), 0.f);
            kk[d][2] = fmaxf(bf2f(v.z), 0.f); kk[d][3] = fmaxf(bf2f(v.w), 0.f);
        }
#pragma unroll
        for (int e = 0; e < 8; e++) {
            u16x4 vr = vp4[e * 1024 + nn];
            float v0 = bf2f(vr.x), v1 = bf2f(vr.y), v2 = bf2f(vr.z), v3 = bf2f(vr.w);
#pragma unroll
            for (int d = 0; d < 8; d++)
                acc[d][e] += kk[d][0] * v0 + kk[d][1] * v1 + kk[d][2] * v2 + kk[d][3] * v3;
        }
#pragma unroll
        for (int d = 0; d < 8; d++)
            acc[d][8] += kk[d][0] + kk[d][1] + kk[d][2] + kk[d][3];
    }

    __shared__ float red[4][72];
    const int lane = threadIdx.x & 63, wv = threadIdx.x >> 6;
#pragma unroll
    for (int d = 0; d < 8; d++) {
#pragma unroll
        for (int e = 0; e < 9; e++) {
            float v = acc[d][e];
            v += __shfl_xor(v, 1);  v += __shfl_xor(v, 2);
            v += __shfl_xor(v, 4);  v += __shfl_xor(v, 8);
            v += __shfl_xor(v, 16); v += __shfl_xor(v, 32);
            if (lane == 0) red[wv][d * 9 + e] = v;
        }
    }
    __syncthreads();
    if (threadIdx.x < 72) {
        float s = red[0][threadIdx.x] + red[1][threadIdx.x] +
                  red[2][threadIdx.x] + red[3][threadIdx.x];
        kvout[((size_t)(b * 64 + h)) * 72 + threadIdx.x] = s;
    }
}

// ---------------- K4: fused att + proj + BN + residual, bf16 MFMA ------------
// grid (64 nb, 8 b), block 256 = 4 waves (2x2: wave tile 128o x 32n).
// Block tile 256o x 64n, K=512. B-staging computes att on the fly:
// thread t -> head h = kb/8 + (t>>6), pixel n = t&63: 8 q loads, num[9], rcp.
__global__ __launch_bounds__(256) void proj_att(const unsigned short* __restrict__ qkv,
                                                const unsigned short* __restrict__ agg,
                                                const float* __restrict__ kvbuf,
                                                const float* __restrict__ wproj,
                                                const float* __restrict__ gamma,
                                                const float* __restrict__ beta,
                                                const float* __restrict__ mean,
                                                const float* __restrict__ var,
                                                const float* __restrict__ x,
                                                float* __restrict__ out) {
    __shared__ short A_l[256 * 40];     // 20 KB
    __shared__ short B_l[64 * 40];      // 5 KB
    __shared__ float kv_l[64 * 72];     // 18.4 KB
    __shared__ float inv_l[256], sh_l[256];
    const int t  = threadIdx.x;
    const int b  = blockIdx.y;
    const int nb = blockIdx.x * 64;

    for (int i = t; i < 64 * 72; i += 256) kv_l[i] = kvbuf[(size_t)b * 64 * 72 + i];
    {
        const float iv = gamma[t] * rsqrtf(var[t] + BN_EPS);
        inv_l[t] = iv;
        sh_l[t]  = beta[t] - mean[t] * iv;
    }

    const int lane = t & 63, wave = t >> 6;
    const int wo = (wave >> 1) * 128, wn = (wave & 1) * 32;

    f32x4 acc[8][2];
#pragma unroll
    for (int s = 0; s < 8; s++)
#pragma unroll
        for (int u = 0; u < 2; u++) acc[s][u] = (f32x4){0.f, 0.f, 0.f, 0.f};

    const int col4 = (t & 7) * 4;
    const int r0   = t >> 3;            // 0..31
    const int hl   = t >> 6;            // 0..3  (B-staging head slot)
    const int np   = t & 63;            // B-staging pixel

    for (int kb = 0; kb < 512; kb += 32) {
        __syncthreads();
        // ---- stage A: wproj[0..255][kb..kb+31] -> bf16 ----
#pragma unroll
        for (int i = 0; i < 8; i++) {
            const int r = r0 + 32 * i;
            float4 v = *(const float4*)&wproj[r * 512 + kb + col4];
            short4v s4 = {f2bf(v.x), f2bf(v.y), f2bf(v.z), f2bf(v.w)};
            *(short4v*)&A_l[r * 40 + col4] = s4;
        }
        // ---- stage B: compute att for (head h, pixel nb+np) ----
        {
            const int h = (kb >> 3) + hl;
            const unsigned short* buf = (h < 32) ? qkv : agg;
            const int cbase = (h & 31) * 24;
            const unsigned short* qp = buf + ((size_t)b * 768 + cbase) * HW + nb + np;

            float num[9];
#pragma unroll
            for (int e = 0; e < 9; e++) num[e] = 0.f;
#pragma unroll
            for (int d = 0; d < 8; d++) {
                const float qv = fmaxf(bf2f(qp[(size_t)d * HW]), 0.f);
                const float* kvh = &kv_l[h * 72 + d * 9];
#pragma unroll
                for (int e = 0; e < 9; e++) num[e] += qv * kvh[e];
            }
            const float rden = 1.f / (num[8] + ATT_EPS);
            short4v lo = {f2bf(num[0] * rden), f2bf(num[1] * rden),
                          f2bf(num[2] * rden), f2bf(num[3] * rden)};
            short4v hi = {f2bf(num[4] * rden), f2bf(num[5] * rden),
                          f2bf(num[6] * rden), f2bf(num[7] * rden)};
            *(short4v*)&B_l[np * 40 + hl * 8]     = lo;
            *(short4v*)&B_l[np * 40 + hl * 8 + 4] = hi;
        }
        __syncthreads();

        short8 af[8], bfr[2];
#pragma unroll
        for (int s = 0; s < 8; s++)
            af[s] = *(const short8*)&A_l[(wo + s * 16 + (lane & 15)) * 40 + (lane >> 4) * 8];
#pragma unroll
        for (int u = 0; u < 2; u++)
            bfr[u] = *(const short8*)&B_l[(wn + u * 16 + (lane & 15)) * 40 + (lane >> 4) * 8];
#pragma unroll
        for (int s = 0; s < 8; s++)
#pragma unroll
            for (int u = 0; u < 2; u++)
                acc[s][u] = __builtin_amdgcn_mfma_f32_16x16x32_bf16(af[s], bfr[u], acc[s][u], 0, 0, 0);
    }

#pragma unroll
    for (int s = 0; s < 8; s++)
#pragma unroll
        for (int u = 0; u < 2; u++)
#pragma unroll
            for (int r = 0; r < 4; r++) {
                const int o = wo + s * 16 + (lane >> 4) * 4 + r;
                const int n = nb + wn + u * 16 + (lane & 15);
                const size_t idx = ((size_t)b * 256 + o) * HW + n;
                out[idx] = x[idx] + acc[s][u][r] * inv_l[o] + sh_l[o];
            }
}

extern "C" void kernel_launch(void* const* d_in, const int* in_sizes, int n_in,
                              void* d_out, int out_size, void* d_ws, size_t ws_size,
                              hipStream_t stream) {
    const float* x      = (const float*)d_in[0];
    const float* w_qkv  = (const float*)d_in[1];
    const float* w_dw   = (const float*)d_in[2];
    const float* w_pw   = (const float*)d_in[3];
    const float* w_proj = (const float*)d_in[4];
    const float* gamma  = (const float*)d_in[5];
    const float* beta   = (const float*)d_in[6];
    const float* mean   = (const float*)d_in[7];
    const float* var    = (const float*)d_in[8];
    float* out = (float*)d_out;

    unsigned short* qkv = (unsigned short*)d_ws;     // 25165824 shorts (50.3 MB)
    unsigned short* agg = qkv + (size_t)25165824;    // 25165824 shorts
    float* kvb = (float*)(agg + (size_t)25165824);   // 8*64*72 floats

    qkv_gemm<<<dim3(32, 6, 8),  256, 0, stream>>>(x, w_qkv, qkv);
    dw_agg  <<<dim3(4, 96, 8),  256, 0, stream>>>(qkv, w_dw, w_pw, agg);
    kv_pass <<<dim3(64, 8),     256, 0, stream>>>(qkv, agg, kvb);
    proj_att<<<dim3(64, 8),     256, 0, stream>>>(qkv, agg, kvb, w_proj,
                                                  gamma, beta, mean, var, x, out);
}

// Round 7
// 261.409 us; speedup vs baseline: 4.3149x; 1.1798x over previous
//
#include <hip/hip_runtime.h>
#include <hip/hip_bf16.h>

// LiteMLA: B=8, C=256, H=W=64, N=HW=4096, td=256, d=8, heads=64
// ws: qkv bf16 (8,768,4096) | agg bf16 (8,768,4096) | att_f bf16 (8,64,4096,8)
//     | w_projbf bf16 (256,512) | kvb f32 (8,64,72)
// Pipeline: prep_w, qkv_gemm (MFMA), dw_agg (fused dw5x5+pw8x8), kv_pass,
//           att_pass (-> att_f fragment-ready layout), proj_gemm (LDS-free MFMA)

#define HW 4096
#define ATT_EPS 1e-15f
#define BN_EPS 1e-6f

typedef __attribute__((ext_vector_type(8))) short short8;
typedef __attribute__((ext_vector_type(4))) short short4v;
typedef __attribute__((ext_vector_type(4))) float f32x4;
typedef __attribute__((ext_vector_type(8))) unsigned short u16x8;
typedef __attribute__((ext_vector_type(4))) unsigned short u16x4;

static __device__ inline short f2bf(float f) {
    union { float f; unsigned u; } v; v.f = f;
    unsigned r = v.u + 0x7fff + ((v.u >> 16) & 1);   // RNE, finite inputs
    return (short)(r >> 16);
}
static __device__ inline float bf2f(unsigned short u) {
    union { unsigned u; float f; } v; v.u = (unsigned)u << 16; return v.f;
}

// ---------------- K0: w_proj f32 -> bf16 (256x512) ----------------
__global__ __launch_bounds__(256) void prep_w(const float* __restrict__ wproj,
                                              unsigned short* __restrict__ wbf) {
    const int i = (blockIdx.x * 256 + threadIdx.x) * 4;   // 131072 / 4 = 32768 thr
    float4 v = *(const float4*)&wproj[i];
    u16x4 r = {(unsigned short)f2bf(v.x), (unsigned short)f2bf(v.y),
               (unsigned short)f2bf(v.z), (unsigned short)f2bf(v.w)};
    *(u16x4*)&wbf[i] = r;
}

// ---------------- K1: qkv(bf16) = W(768x256) @ X(256x4096), bf16 MFMA --------
// grid (32 nb, 6 ob, 8 b), block 256 = 4 waves (2x2). Tile 128o x 128n, BK=32.
__global__ __launch_bounds__(256) void qkv_gemm(const float* __restrict__ x,
                                                const float* __restrict__ w,
                                                unsigned short* __restrict__ qkv) {
    __shared__ short A_l[128 * 40];
    __shared__ short B_l[128 * 40];
    const int t  = threadIdx.x;
    const int b  = blockIdx.z;
    const int ob = blockIdx.y * 128;
    const int nb = blockIdx.x * 128;
    const float* xb = x + (size_t)b * 256 * HW;

    const int lane = t & 63, wave = t >> 6;
    const int wo = (wave >> 1) * 64, wn = (wave & 1) * 64;

    f32x4 acc[4][4];
#pragma unroll
    for (int s = 0; s < 4; s++)
#pragma unroll
        for (int u = 0; u < 4; u++) acc[s][u] = (f32x4){0.f, 0.f, 0.f, 0.f};

    const int col4 = (t & 7) * 4;
    const int r0   = t >> 3;            // 0..31
    for (int kb = 0; kb < 256; kb += 32) {
        __syncthreads();
#pragma unroll
        for (int i = 0; i < 4; i++) {
            const int r = r0 + 32 * i;
            float4 v = *(const float4*)&w[(ob + r) * 256 + kb + col4];
            short4v s4 = {f2bf(v.x), f2bf(v.y), f2bf(v.z), f2bf(v.w)};
            *(short4v*)&A_l[r * 40 + col4] = s4;
        }
#pragma unroll
        for (int i = 0; i < 4; i++) {
            const int n4 = (t & 7) + 8 * i;
            float4 v = *(const float4*)&xb[(size_t)(kb + r0) * HW + nb + n4 * 4];
            B_l[(n4 * 4 + 0) * 40 + r0] = f2bf(v.x);
            B_l[(n4 * 4 + 1) * 40 + r0] = f2bf(v.y);
            B_l[(n4 * 4 + 2) * 40 + r0] = f2bf(v.z);
            B_l[(n4 * 4 + 3) * 40 + r0] = f2bf(v.w);
        }
        __syncthreads();

        short8 af[4], bf[4];
#pragma unroll
        for (int s = 0; s < 4; s++)
            af[s] = *(const short8*)&A_l[(wo + s * 16 + (lane & 15)) * 40 + (lane >> 4) * 8];
#pragma unroll
        for (int u = 0; u < 4; u++)
            bf[u] = *(const short8*)&B_l[(wn + u * 16 + (lane & 15)) * 40 + (lane >> 4) * 8];
#pragma unroll
        for (int s = 0; s < 4; s++)
#pragma unroll
            for (int u = 0; u < 4; u++)
                acc[s][u] = __builtin_amdgcn_mfma_f32_16x16x32_bf16(af[s], bf[u], acc[s][u], 0, 0, 0);
    }

#pragma unroll
    for (int s = 0; s < 4; s++)
#pragma unroll
        for (int u = 0; u < 4; u++)
#pragma unroll
            for (int r = 0; r < 4; r++) {
                const int o = ob + wo + s * 16 + (lane >> 4) * 4 + r;
                const int n = nb + wn + u * 16 + (lane & 15);
                qkv[((size_t)b * 768 + o) * HW + n] = (unsigned short)f2bf(acc[s][u][r]);
            }
}

// ---------------- K2: fused depthwise 5x5 + grouped pointwise 8x8 ------------
__global__ __launch_bounds__(256) void dw_agg(const unsigned short* __restrict__ qkv,
                                              const float* __restrict__ wdw,
                                              const float* __restrict__ wpw,
                                              unsigned short* __restrict__ agg) {
    __shared__ float in_t[8][20][68];   // 43.5 KB
    __shared__ float wk[8][25];
    __shared__ float pw[64];
    const int b = blockIdx.z, g = blockIdx.y;
    const int y0 = blockIdx.x * 16;
    const int t = threadIdx.x;

    float4* zp = (float4*)in_t;
    for (int i = t; i < 8 * 20 * 68 / 4; i += 256) zp[i] = make_float4(0.f, 0.f, 0.f, 0.f);
    if (t < 200) wk[t / 25][t % 25] = wdw[(g * 8) * 25 + t];
    if (t < 64)  pw[t] = wpw[g * 64 + t];
    __syncthreads();

    for (int i = t; i < 1280; i += 256) {
        const int ch = i / 160, rem = i % 160;
        const int r = rem >> 3, c8 = rem & 7;
        const int y = y0 - 2 + r;
        if (y >= 0 && y < 64) {
            const unsigned short* src =
                qkv + ((size_t)(b * 768 + g * 8 + ch)) * HW + y * 64 + c8 * 8;
            u16x8 v = *(const u16x8*)src;
            float* dp = &in_t[ch][r][2 + c8 * 8];
#pragma unroll
            for (int j = 0; j < 8; j++) dp[j] = bf2f(v[j]);
        }
    }
    __syncthreads();

    const int tx = t & 15, ty = t >> 4;
    float dwres[8][4];
#pragma unroll
    for (int ch = 0; ch < 8; ch++) {
        float a0 = 0.f, a1 = 0.f, a2 = 0.f, a3 = 0.f;
#pragma unroll
        for (int dy = 0; dy < 5; dy++) {
            const float* rp = &in_t[ch][ty + dy][tx * 4];
            float4 f0 = *(const float4*)rp;
            float4 f1 = *(const float4*)(rp + 4);
            float win[8] = {f0.x, f0.y, f0.z, f0.w, f1.x, f1.y, f1.z, f1.w};
#pragma unroll
            for (int dx = 0; dx < 5; dx++) {
                const float wv = wk[ch][dy * 5 + dx];
                a0 += wv * win[dx + 0];
                a1 += wv * win[dx + 1];
                a2 += wv * win[dx + 2];
                a3 += wv * win[dx + 3];
            }
        }
        dwres[ch][0] = a0; dwres[ch][1] = a1; dwres[ch][2] = a2; dwres[ch][3] = a3;
    }
#pragma unroll
    for (int o = 0; o < 8; o++) {
        float s0 = 0.f, s1 = 0.f, s2 = 0.f, s3 = 0.f;
#pragma unroll
        for (int i = 0; i < 8; i++) {
            const float wv = pw[o * 8 + i];
            s0 += wv * dwres[i][0]; s1 += wv * dwres[i][1];
            s2 += wv * dwres[i][2]; s3 += wv * dwres[i][3];
        }
        u16x4 rv = {(unsigned short)f2bf(s0), (unsigned short)f2bf(s1),
                    (unsigned short)f2bf(s2), (unsigned short)f2bf(s3)};
        *(u16x4*)&agg[((size_t)(b * 768 + g * 8 + o)) * HW + (y0 + ty) * 64 + tx * 4] = rv;
    }
}

// ---------------- K3: kv[d][e] = sum_n relu(k[n,d]) * vpad[n,e], bf16 in -----
__global__ __launch_bounds__(256) void kv_pass(const unsigned short* __restrict__ qkv,
                                               const unsigned short* __restrict__ agg,
                                               float* __restrict__ kvout) {
    const int h = blockIdx.x, b = blockIdx.y;
    const unsigned short* buf = (h < 32) ? qkv : agg;
    const int cbase = (h < 32) ? h * 24 : (h - 32) * 24;
    const u16x4* kp4 = (const u16x4*)(buf + ((size_t)b * 768 + cbase + 8)  * HW);
    const u16x4* vp4 = (const u16x4*)(buf + ((size_t)b * 768 + cbase + 16) * HW);

    float acc[8][9];
#pragma unroll
    for (int d = 0; d < 8; d++)
#pragma unroll
        for (int e = 0; e < 9; e++) acc[d][e] = 0.f;

#pragma unroll
    for (int k = 0; k < 4; k++) {
        const int nn = threadIdx.x + k * 256;
        float kk[8][4];
#pragma unroll
        for (int d = 0; d < 8; d++) {
            u16x4 v = kp4[d * 1024 + nn];
            kk[d][0] = fmaxf(bf2f(v.x), 0.f); kk[d][1] = fmaxf(bf2f(v.y), 0.f);
            kk[d][2] = fmaxf(bf2f(v.z), 0.f); kk[d][3] = fmaxf(bf2f(v.w), 0.f);
        }
#pragma unroll
        for (int e = 0; e < 8; e++) {
            u16x4 vr = vp4[e * 1024 + nn];
            float v0 = bf2f(vr.x), v1 = bf2f(vr.y), v2 = bf2f(vr.z), v3 = bf2f(vr.w);
#pragma unroll
            for (int d = 0; d < 8; d++)
                acc[d][e] += kk[d][0] * v0 + kk[d][1] * v1 + kk[d][2] * v2 + kk[d][3] * v3;
        }
#pragma unroll
        for (int d = 0; d < 8; d++)
            acc[d][8] += kk[d][0] + kk[d][1] + kk[d][2] + kk[d][3];
    }

    __shared__ float red[4][72];
    const int lane = threadIdx.x & 63, wv = threadIdx.x >> 6;
#pragma unroll
    for (int d = 0; d < 8; d++) {
#pragma unroll
        for (int e = 0; e < 9; e++) {
            float v = acc[d][e];
            v += __shfl_xor(v, 1);  v += __shfl_xor(v, 2);
            v += __shfl_xor(v, 4);  v += __shfl_xor(v, 8);
            v += __shfl_xor(v, 16); v += __shfl_xor(v, 32);
            if (lane == 0) red[wv][d * 9 + e] = v;
        }
    }
    __syncthreads();
    if (threadIdx.x < 72) {
        float s = red[0][threadIdx.x] + red[1][threadIdx.x] +
                  red[2][threadIdx.x] + red[3][threadIdx.x];
        kvout[((size_t)(b * 64 + h)) * 72 + threadIdx.x] = s;
    }
}

// ---------------- K4: att -> att_f[b][h][n][8] (B-fragment-ready bf16) -------
// grid (2 nb, 64 h, 8 b), block 256; thread = 8 consecutive px.
__global__ __launch_bounds__(256) void att_pass(const unsigned short* __restrict__ qkv,
                                                const unsigned short* __restrict__ agg,
                                                const float* __restrict__ kvbuf,
                                                unsigned short* __restrict__ att_f) {
    __shared__ float kvl[72];
    const int h = blockIdx.y, b = blockIdx.z;
    const int t = threadIdx.x;
    if (t < 72) kvl[t] = kvbuf[((size_t)(b * 64 + h)) * 72 + t];
    __syncthreads();

    const unsigned short* buf = (h < 32) ? qkv : agg;
    const int cbase = (h & 31) * 24;
    const int n0 = (blockIdx.x * 256 + t) * 8;     // 8 px per thread
    const unsigned short* qp = buf + ((size_t)b * 768 + cbase) * HW + n0;

    float q[8][8];                                  // [d][px]
#pragma unroll
    for (int d = 0; d < 8; d++) {
        u16x8 v = *(const u16x8*)&qp[(size_t)d * HW];
#pragma unroll
        for (int j = 0; j < 8; j++) q[d][j] = fmaxf(bf2f(v[j]), 0.f);
    }

    unsigned short* op = att_f + (((size_t)(b * 64 + h)) * HW + n0) * 8;
#pragma unroll
    for (int j = 0; j < 8; j++) {
        float num[9];
#pragma unroll
        for (int e = 0; e < 9; e++) num[e] = 0.f;
#pragma unroll
        for (int d = 0; d < 8; d++) {
            const float qv = q[d][j];
            const float* kvh = &kvl[d * 9];
#pragma unroll
            for (int e = 0; e < 9; e++) num[e] += qv * kvh[e];
        }
        const float rden = 1.f / (num[8] + ATT_EPS);
        u16x8 r;
#pragma unroll
        for (int e = 0; e < 8; e++) r[e] = (unsigned short)f2bf(num[e] * rden);
        *(u16x8*)&op[j * 8] = r;
    }
}

// ---------------- K5: p = Wp @ att, BN, +x — LDS-free direct-frag MFMA -------
// grid (32 nb, 2 ob, 8 b), block 256 = 4 waves (2x2), wave tile 64o x 64n.
// A frags: u16x8 direct from bf16 weights (L2). B frags: u16x8 from att_f.
// No __syncthreads in the K-loop at all.
__global__ __launch_bounds__(256) void proj_gemm(const unsigned short* __restrict__ wbf,
                                                 const unsigned short* __restrict__ att_f,
                                                 const float* __restrict__ gamma,
                                                 const float* __restrict__ beta,
                                                 const float* __restrict__ mean,
                                                 const float* __restrict__ var,
                                                 const float* __restrict__ x,
                                                 float* __restrict__ out) {
    const int t  = threadIdx.x;
    const int b  = blockIdx.z;
    const int ob = blockIdx.y * 128;
    const int nb = blockIdx.x * 128;
    const int lane = t & 63, wave = t >> 6;
    const int wo = (wave >> 1) * 64, wn = (wave & 1) * 64;

    const int am = lane & 15, ak = lane >> 4;       // frag row / k-octet
    const unsigned short* ap0 = wbf + (size_t)(ob + wo + am) * 512 + ak * 8;
    const unsigned short* bp0 = att_f +
        (((size_t)b * 64 + ak) * HW + nb + wn + am) * 8;

    f32x4 acc[4][4];
#pragma unroll
    for (int s = 0; s < 4; s++)
#pragma unroll
        for (int u = 0; u < 4; u++) acc[s][u] = (f32x4){0.f, 0.f, 0.f, 0.f};

    for (int kb = 0; kb < 512; kb += 32) {
        short8 af[4], bf[4];
#pragma unroll
        for (int s = 0; s < 4; s++)
            af[s] = *(const short8*)(ap0 + (size_t)s * 16 * 512 + kb);
#pragma unroll
        for (int u = 0; u < 4; u++)
            bf[u] = *(const short8*)(bp0 + ((size_t)(kb >> 3) * HW + u * 16) * 8);
#pragma unroll
        for (int s = 0; s < 4; s++)
#pragma unroll
            for (int u = 0; u < 4; u++)
                acc[s][u] = __builtin_amdgcn_mfma_f32_16x16x32_bf16(af[s], bf[u], acc[s][u], 0, 0, 0);
    }

#pragma unroll
    for (int s = 0; s < 4; s++) {
        const int o_base = ob + wo + s * 16 + (lane >> 4) * 4;
#pragma unroll
        for (int r = 0; r < 4; r++) {
            const int o = o_base + r;
            const float inv = gamma[o] * rsqrtf(var[o] + BN_EPS);
            const float sh  = beta[o] - mean[o] * inv;
#pragma unroll
            for (int u = 0; u < 4; u++) {
                const int n = nb + wn + u * 16 + (lane & 15);
                const size_t idx = ((size_t)b * 256 + o) * HW + n;
                out[idx] = x[idx] + acc[s][u][r] * inv + sh;
            }
        }
    }
}

extern "C" void kernel_launch(void* const* d_in, const int* in_sizes, int n_in,
                              void* d_out, int out_size, void* d_ws, size_t ws_size,
                              hipStream_t stream) {
    const float* x      = (const float*)d_in[0];
    const float* w_qkv  = (const float*)d_in[1];
    const float* w_dw   = (const float*)d_in[2];
    const float* w_pw   = (const float*)d_in[3];
    const float* w_proj = (const float*)d_in[4];
    const float* gamma  = (const float*)d_in[5];
    const float* beta   = (const float*)d_in[6];
    const float* mean   = (const float*)d_in[7];
    const float* var    = (const float*)d_in[8];
    float* out = (float*)d_out;

    unsigned short* qkv  = (unsigned short*)d_ws;      // 25165824 shorts
    unsigned short* agg  = qkv + (size_t)25165824;     // 25165824 shorts
    unsigned short* attf = agg + (size_t)25165824;     // 16777216 shorts
    unsigned short* wbf  = attf + (size_t)16777216;    // 131072 shorts
    float* kvb = (float*)(wbf + (size_t)131072);       // 36864 floats

    prep_w  <<<dim3(128),       256, 0, stream>>>(w_proj, wbf);
    qkv_gemm<<<dim3(32, 6, 8),  256, 0, stream>>>(x, w_qkv, qkv);
    dw_agg  <<<dim3(4, 96, 8),  256, 0, stream>>>(qkv, w_dw, w_pw, agg);
    kv_pass <<<dim3(64, 8),     256, 0, stream>>>(qkv, agg, kvb);
    att_pass<<<dim3(2, 64, 8),  256, 0, stream>>>(qkv, agg, kvb, attf);
    proj_gemm<<<dim3(32, 2, 8), 256, 0, stream>>>(wbf, attf,
                                                  gamma, beta, mean, var, x, out);
}